// Round 4
// baseline (420.371 us; speedup 1.0000x reference)
//
#include <hip/hip_runtime.h>
#include <math.h>

#define B_  128
#define S_  512
#define U_  1024
#define T_  48
#define CHK 32      // steps per chunk operator
#define NCH 16      // max chunks per batch = ceil((S-1)/CHK)
#define PLD 72      // P row stride in bf16 elems (144 B, 16B-aligned rows)

typedef short  bf16x8 __attribute__((ext_vector_type(8)));
typedef float  f32x4  __attribute__((ext_vector_type(4)));

__device__ __forceinline__ float rfl(float x) {
    return __int_as_float(__builtin_amdgcn_readfirstlane(__float_as_int(x)));
}
// round-to-nearest fp32 -> bf16 bits, packed pairwise
__device__ __forceinline__ unsigned pack_bf16(float lo, float hi) {
    const unsigned a = __float_as_uint(lo) + 0x8000u;
    const unsigned b = __float_as_uint(hi) + 0x8000u;
    return __builtin_amdgcn_perm(b, a, 0x07060302u);
}

// ===========================================================================
// Kernel 0: Wt[n][k] = bf16(W[k][n])  (one-time transpose for gemm B staging)
// ===========================================================================
__global__ __launch_bounds__(256) void prep_w(
    const float* __restrict__ W, unsigned short* __restrict__ Wt)
{
    const int n = blockIdx.x;                 // 48 blocks
#pragma unroll
    for (int i = 0; i < 4; ++i) {
        const int k = threadIdx.x + 256 * i;
        const unsigned u = __float_as_uint(W[(size_t)k * T_ + n]) + 0x8000u;
        Wt[(size_t)n * U_ + k] = (unsigned short)(u >> 16);
    }
}

// ===========================================================================
// Kernel 1: scores = H @ W + b (fp32). MFMA bf16 16x16x32.
// T14 reg-staged prefetch: loads for kc+1 issue BEFORE the pack of kc, so
// the pack waits on a counted vmcnt (never a full drain) and HBM latency
// hides under pack+barrier+MFMA. Load-row clamp at the s_len boundary kept.
// ===========================================================================
#define KC     64
#define HS_LD  72
#define WS_LD  72

// issue global loads for k-chunk `kc` into register sets H_ (8x float4) and
// W_ (up to 2x uint4); no waits here.
#define G_ISSUE(kc, H_, W_)                                              \
    {                                                                    \
        const int k0_ = (kc) * KC;                                       \
        _Pragma("unroll")                                                \
        for (int p = 0; p < 8; ++p) {                                    \
            const int row_ = p * 16 + grp;                               \
            const int rl_  = row_ < lim ? row_ : lim;                    \
            H_[p] = *reinterpret_cast<const float4*>(                    \
                Hg + (size_t)rl_ * U_ + k0_ + l16 * 4);                  \
        }                                                                \
        W_[0] = *reinterpret_cast<const uint4*>(                         \
            Wt + (size_t)(tid >> 3) * U_ + k0_ + (tid & 7) * 8);         \
        if (tid < 128)                                                   \
            W_[1] = *reinterpret_cast<const uint4*>(                     \
                Wt + (size_t)((tid + 256) >> 3) * U_ + k0_ +             \
                (tid & 7) * 8);                                          \
    }

// process k-chunk `kc` held in H_/W_, prefetching kc+1 into HN_/WN_ first
#define G_STEP(kc, H_, W_, HN_, WN_)                                     \
    {                                                                    \
        if ((kc) + 1 < U_ / KC) G_ISSUE((kc) + 1, HN_, WN_);             \
        _Pragma("unroll")                                                \
        for (int p = 0; p < 8; ++p) {                                    \
            const int row_ = p * 16 + grp;                               \
            const unsigned p01 = pack_bf16(H_[p].x, H_[p].y);            \
            const unsigned p23 = pack_bf16(H_[p].z, H_[p].w);            \
            *reinterpret_cast<uint2*>(&Hs[row_ * HS_LD + l16 * 4]) =     \
                make_uint2(p01, p23);                                    \
        }                                                                \
        *reinterpret_cast<uint4*>(                                       \
            &Ws[(tid >> 3) * WS_LD + (tid & 7) * 8]) = W_[0];            \
        if (tid < 128)                                                   \
            *reinterpret_cast<uint4*>(                                   \
                &Ws[((tid + 256) >> 3) * WS_LD + (tid & 7) * 8]) = W_[1];\
        __syncthreads();                                                 \
        bf16x8 afr[2][2], bfr[3][2];                                     \
        _Pragma("unroll")                                                \
        for (int mt = 0; mt < 2; ++mt)                                   \
            _Pragma("unroll")                                            \
            for (int ks = 0; ks < 2; ++ks)                               \
                afr[mt][ks] = *reinterpret_cast<const bf16x8*>(          \
                    &Hs[(wave * 32 + mt * 16 + m16) * HS_LD +            \
                        ks * 32 + q * 8]);                               \
        _Pragma("unroll")                                                \
        for (int nt = 0; nt < 3; ++nt)                                   \
            _Pragma("unroll")                                            \
            for (int ks = 0; ks < 2; ++ks)                               \
                bfr[nt][ks] = *reinterpret_cast<const bf16x8*>(          \
                    &Ws[(nt * 16 + m16) * WS_LD + ks * 32 + q * 8]);     \
        _Pragma("unroll")                                                \
        for (int ks = 0; ks < 2; ++ks)                                   \
            _Pragma("unroll")                                            \
            for (int mt = 0; mt < 2; ++mt)                               \
                _Pragma("unroll")                                        \
                for (int nt = 0; nt < 3; ++nt)                           \
                    acc[mt][nt] = __builtin_amdgcn_mfma_f32_16x16x32_bf16(\
                        afr[mt][ks], bfr[nt][ks], acc[mt][nt], 0, 0, 0); \
        __syncthreads();                                                 \
    }

__global__ __launch_bounds__(256, 2) void gemm_scores_mfma(
    const float* __restrict__ H, const unsigned short* __restrict__ Wt,
    const float* __restrict__ bias, const int* __restrict__ s_len,
    float* __restrict__ scores)
{
    __shared__ unsigned short Hs[128 * HS_LD];
    __shared__ unsigned short Ws[T_ * WS_LD];

    const int blk = blockIdx.x;
    const int b   = blk >> 2;
    const int s0  = (blk & 3) * 128;
    const int len = s_len[b];
    if (s0 >= len) return;
    const int lim = len - 1 - s0;             // >= 0; clamp row for loads

    const int tid  = threadIdx.x;
    const int wave = tid >> 6;
    const int lane = tid & 63;
    const int m16  = lane & 15;
    const int q    = lane >> 4;
    const int grp  = tid >> 4;
    const int l16  = tid & 15;

    const size_t row0 = (size_t)b * S_ + s0;
    const float* Hg = H + row0 * U_;

    f32x4 acc[2][3];
#pragma unroll
    for (int mt = 0; mt < 2; ++mt)
#pragma unroll
        for (int nt = 0; nt < 3; ++nt) acc[mt][nt] = (f32x4){0.f, 0.f, 0.f, 0.f};

    float4 ha[8], hb[8];
    uint4  wa[2], wb2[2];

    G_ISSUE(0, ha, wa);
    for (int kc = 0; kc < U_ / KC; kc += 2) {
        G_STEP(kc,     ha, wa,  hb, wb2);
        G_STEP(kc + 1, hb, wb2, ha, wa);
    }

#pragma unroll
    for (int mt = 0; mt < 2; ++mt)
#pragma unroll
        for (int nt = 0; nt < 3; ++nt) {
            const int col = nt * 16 + m16;
            const float bv = bias[col];
#pragma unroll
            for (int i = 0; i < 4; ++i) {
                const size_t r = row0 + wave * 32 + mt * 16 + q * 4 + i;
                scores[r * T_ + col] = acc[mt][nt][i] + bv;
            }
        }
}

// ===========================================================================
// Kernel 2: build chunk operators with MFMA (parallel scan, chunk = 32 steps,
// PARTIAL chunks included: wave-uniform ns = min(CHK, len - s0) steps, so the
// serial kernel has no scalar tail). One wave per (batch, chunk). Per step
// computes P_new^T = D_em * E^T * P^T; per-step normalization by the lead
// entry, log accumulated. Exports Pt[t][j] = P[j][t] + log-scale.
// ===========================================================================
__global__ __launch_bounds__(256) void build_ops(
    const float* __restrict__ scores, const float* __restrict__ trans,
    const int* __restrict__ s_len,
    unsigned short* __restrict__ Ptg, float* __restrict__ logS)
{
    __shared__ float Eld[T_ * T_];                         // exp(trans)[k][m]
    __shared__ __align__(16) unsigned short Pb[4 * 48 * PLD];

    const int tid  = threadIdx.x;
    const int wid  = tid >> 6;
    const int lane = tid & 63;
    const int m16  = lane & 15;
    const int q    = lane >> 4;

    for (int i = tid; i < T_ * T_; i += 256)
        Eld[i] = __expf(trans[i]);
    __syncthreads();                                       // all waves reach

    const int widx = blockIdx.x * 4 + wid;                 // 0..2047
    const int b    = widx / NCH;
    const int c    = widx % NCH;
    const int len  = s_len[b];
    const int s0   = 1 + c * CHK;
    if (s0 >= len) return;                                 // chunk fully past end
    const int ns   = (len - s0 < CHK) ? (len - s0) : CHK;  // wave-uniform

    unsigned short* Ps = &Pb[wid * 48 * PLD];

    // ---- constant A-fragments of E^T: A[m][k] = E[k][m], k>=48 -> 0 ----
    bf16x8 afr[3][2];
#pragma unroll
    for (int mt = 0; mt < 3; ++mt)
#pragma unroll
        for (int kt = 0; kt < 2; ++kt) {
            union { bf16x8 v; unsigned short s[8]; } u;
#pragma unroll
            for (int j = 0; j < 8; ++j) {
                const int k = kt * 32 + q * 8 + j;
                const int m = mt * 16 + m16;
                const float ev = (k < T_) ? Eld[k * T_ + m] : 0.f;
                u.s[j] = (unsigned short)((__float_as_uint(ev) + 0x8000u) >> 16);
            }
            afr[mt][kt] = u.v;
        }

    // ---- init P = Identity (zeros incl. col pad, then diagonal) ----
    {
        uint4* p4 = reinterpret_cast<uint4*>(Ps);
        const uint4 z = make_uint4(0u, 0u, 0u, 0u);
        for (int i = lane; i < 48 * PLD / 8; i += 64) p4[i] = z;
        __builtin_amdgcn_wave_barrier();
        if (lane < T_) Ps[lane * PLD + lane] = 0x3F80;     // bf16(1.0)
        __builtin_amdgcn_wave_barrier();
    }

    const float* sb = scores + ((size_t)b * S_ + s0) * T_;
    float logacc = 0.f;

    // em prefetch: col block mt*16 + q*4 (+i) -> float4 index mt*4+q
    float4 emld[3];
#pragma unroll
    for (int mt = 0; mt < 3; ++mt)
        emld[mt] = reinterpret_cast<const float4*>(sb)[mt * 4 + q];

    for (int i = 0; i < ns; ++i) {
        float4 em[3];
#pragma unroll
        for (int mt = 0; mt < 3; ++mt) {
            em[mt].x = __expf(emld[mt].x); em[mt].y = __expf(emld[mt].y);
            em[mt].z = __expf(emld[mt].z); em[mt].w = __expf(emld[mt].w);
        }
        if (i + 1 < ns) {
            const float* sn = sb + (i + 1) * T_;
#pragma unroll
            for (int mt = 0; mt < 3; ++mt)
                emld[mt] = reinterpret_cast<const float4*>(sn)[mt * 4 + q];
        }

        // B-fragments: B[k][n] = P^T[k][n] = P[n][k] -> b128 from row n
        bf16x8 bfr[2][3];
#pragma unroll
        for (int kt = 0; kt < 2; ++kt)
#pragma unroll
            for (int nt = 0; nt < 3; ++nt)
                bfr[kt][nt] = *reinterpret_cast<const bf16x8*>(
                    &Ps[(nt * 16 + m16) * PLD + kt * 32 + q * 8]);

        f32x4 acc[3][3];
#pragma unroll
        for (int mt = 0; mt < 3; ++mt)
#pragma unroll
            for (int nt = 0; nt < 3; ++nt) acc[mt][nt] = (f32x4){0.f,0.f,0.f,0.f};
#pragma unroll
        for (int kt = 0; kt < 2; ++kt)
#pragma unroll
            for (int mt = 0; mt < 3; ++mt)
#pragma unroll
                for (int nt = 0; nt < 3; ++nt)
                    acc[mt][nt] = __builtin_amdgcn_mfma_f32_16x16x32_bf16(
                        afr[mt][kt], bfr[kt][nt], acc[mt][nt], 0, 0, 0);

        // normalize by D[0][0]*em[0] (lane 0 holds it), scale rows by em
        const float r    = rfl(acc[0][0][0] * em[0].x);
        const float rinv = __builtin_amdgcn_rcpf(r);
        logacc += __logf(r);
        __builtin_amdgcn_wave_barrier();
#pragma unroll
        for (int mt = 0; mt < 3; ++mt) {
            const float sx = em[mt].x * rinv, sy = em[mt].y * rinv;
            const float sz = em[mt].z * rinv, sw = em[mt].w * rinv;
#pragma unroll
            for (int nt = 0; nt < 3; ++nt) {
                const unsigned lo = pack_bf16(acc[mt][nt][0] * sx,
                                              acc[mt][nt][1] * sy);
                const unsigned hi = pack_bf16(acc[mt][nt][2] * sz,
                                              acc[mt][nt][3] * sw);
                // D[m][n] = P_new[n][m]: row n = nt*16+m16, cols mt*16+q*4..+3
                *reinterpret_cast<uint2*>(
                    &Ps[(nt * 16 + m16) * PLD + mt * 16 + q * 4]) =
                    make_uint2(lo, hi);
            }
        }
        __builtin_amdgcn_wave_barrier();
    }

    // ---- export transposed operator: Pt[t][j] = P[j][t]  (48x48 bf16) ----
    if (lane < T_) {
        unsigned outp[24];
#pragma unroll
        for (int j2 = 0; j2 < 24; ++j2) {
            const unsigned a  = Ps[(2 * j2)     * PLD + lane];
            const unsigned b2 = Ps[(2 * j2 + 1) * PLD + lane];
            outp[j2] = a | (b2 << 16);
        }
        unsigned short* dst =
            Ptg + (((size_t)b * NCH + c) * 48 + lane) * 48;
        uint4* d4 = reinterpret_cast<uint4*>(dst);
#pragma unroll
        for (int t4 = 0; t4 < 6; ++t4)
            d4[t4] = make_uint4(outp[4*t4], outp[4*t4+1],
                                outp[4*t4+2], outp[4*t4+3]);
    }
    if (lane == 0) logS[(size_t)b * NCH + c] = logacc;
}

// ===========================================================================
// Kernel 3: CRF forward + numerator. One wave per batch.
// Pure chunk phase: F = ceil((len-1)/CHK) <= 16 serial steps. Operators are
// prefetched depth-2 (3 rotating register buffers, loop unrolled by 3 so all
// buffer indices are compile-time static -> no scratch, no reg moves).
// Lag-1 normalization invariant unchanged.
// ===========================================================================
#define LOADCH(dst, lsdst, idx)                                          \
    {                                                                    \
        const uint4* p_ = reinterpret_cast<const uint4*>(                \
            Pb_ + (size_t)(idx) * 2304 + (size_t)col * 48);              \
        _Pragma("unroll")                                                \
        for (int i_ = 0; i_ < 6; ++i_) dst[i_] = p_[i_];                 \
        lsdst = Lb[idx];                                                 \
    }

#define CRF_BODY(CUR, CL, N2, N2L, CC)                                   \
    {                                                                    \
        if ((CC) + 2 < F) LOADCH(N2, N2L, (CC) + 2);                     \
        float pr[48];                                                    \
        _Pragma("unroll")                                                \
        for (int i_ = 0; i_ < 6; ++i_) {                                 \
            const uint4 u = CUR[i_];                                     \
            pr[8*i_+0] = __uint_as_float(u.x << 16);                     \
            pr[8*i_+1] = __uint_as_float(u.x & 0xFFFF0000u);             \
            pr[8*i_+2] = __uint_as_float(u.y << 16);                     \
            pr[8*i_+3] = __uint_as_float(u.y & 0xFFFF0000u);             \
            pr[8*i_+4] = __uint_as_float(u.z << 16);                     \
            pr[8*i_+5] = __uint_as_float(u.z & 0xFFFF0000u);             \
            pr[8*i_+6] = __uint_as_float(u.w << 16);                     \
            pr[8*i_+7] = __uint_as_float(u.w & 0xFFFF0000u);             \
        }                                                                \
        wb[par & 1][lane] = v;                                           \
        __builtin_amdgcn_wave_barrier();                                 \
        const float4* a4 = reinterpret_cast<const float4*>(wb[par & 1]); \
        float d0=0.f,d1=0.f,d2=0.f,d3=0.f,d4=0.f,d5=0.f,d6=0.f,d7=0.f;   \
        _Pragma("unroll")                                                \
        for (int j4 = 0; j4 < 6; ++j4) {                                 \
            const float4 pa = a4[2 * j4];                                \
            const float4 pb = a4[2 * j4 + 1];                            \
            d0 = fmaf(pa.x, pr[8*j4+0], d0);                             \
            d1 = fmaf(pa.y, pr[8*j4+1], d1);                             \
            d2 = fmaf(pa.z, pr[8*j4+2], d2);                             \
            d3 = fmaf(pa.w, pr[8*j4+3], d3);                             \
            d4 = fmaf(pb.x, pr[8*j4+4], d4);                             \
            d5 = fmaf(pb.y, pr[8*j4+5], d5);                             \
            d6 = fmaf(pb.z, pr[8*j4+6], d6);                             \
            d7 = fmaf(pb.w, pr[8*j4+7], d7);                             \
        }                                                                \
        __builtin_amdgcn_wave_barrier();                                 \
        const float dt = ((d0 + d4) + (d1 + d5)) + ((d2 + d6) + (d3 + d7));\
        v = dt * invr;                                                   \
        C += lr + CL;                                                    \
        const float r_ = rfl(v);                                         \
        invr = __builtin_amdgcn_rcpf(r_);                                \
        lr   = __logf(r_);                                               \
        par ^= 1;                                                        \
    }

__global__ __launch_bounds__(64) void crf_forward(
    const float* __restrict__ scores, const unsigned short* __restrict__ Ptg,
    const float* __restrict__ logS,
    const float* __restrict__ start_tr, const float* __restrict__ end_tr,
    const float* __restrict__ trans, const int* __restrict__ tag,
    const int* __restrict__ s_len, float* __restrict__ out)
{
    __shared__ float Tr[T_ * T_];
    __shared__ __align__(16) float wb[2][64];

    const int b    = blockIdx.x;
    const int lane = threadIdx.x;

    for (int i = lane; i < T_ * T_; i += 64)
        Tr[i] = trans[i];
    __syncthreads();

    const int len = s_len[b];                       // [1, S]
    const float* sc = scores + (size_t)b * S_ * T_;
    const int*   tg = tag + (size_t)b * S_;

    // ---- numerator ----
    float nsum = 0.f;
    for (int s = lane; s < len; s += 64) {
        const int t = tg[s];
        nsum += sc[s * T_ + t];
        if (s >= 1) nsum += Tr[tg[s - 1] * T_ + t];
    }
#pragma unroll
    for (int off = 32; off >= 1; off >>= 1)
        nsum += __shfl_xor(nsum, off);

    const int col = (lane < T_) ? lane : 0;

    // ---- init from step 0 ----
    const float lp0 = (lane < T_) ? (start_tr[lane] + sc[lane]) : -1e30f;
    const float m0  = rfl(lp0);
    float v = __expf(lp0 - m0);
    float C = m0;
    float invr = 1.0f, lr = 0.0f;
    int par = 0;

    // ---- chunk phase (covers ALL steps 1..len-1) ----
    const int F = (len - 1 + CHK - 1) / CHK;
    const unsigned short* Pb_ = Ptg + (size_t)b * NCH * 48 * 48;
    const float* Lb = logS + (size_t)b * NCH;

    uint4 c0[6], c1[6], c2[6];
    float l0_ = 0.f, l1_ = 0.f, l2_ = 0.f;
    if (F > 0) LOADCH(c0, l0_, 0);
    if (F > 1) LOADCH(c1, l1_, 1);

    int cc = 0;
    while (cc + 3 <= F) {
        CRF_BODY(c0, l0_, c2, l2_, cc);
        CRF_BODY(c1, l1_, c0, l0_, cc + 1);
        CRF_BODY(c2, l2_, c1, l1_, cc + 2);
        cc += 3;
    }
    if (cc < F) {
        CRF_BODY(c0, l0_, c2, l2_, cc); ++cc;
        if (cc < F) { CRF_BODY(c1, l1_, c0, l0_, cc); ++cc; }
    }

    // ---- log_Z = C + log(sum_t v_t * exp(end_t)) ----
    // (pending lr is correctly NOT applied: invariant log(alpha)=log(v)+C)
    float z = (lane < T_) ? v * __expf(end_tr[lane]) : 0.f;
#pragma unroll
    for (int off = 32; off >= 1; off >>= 1)
        z += __shfl_xor(z, off);
    const float logZ = C + __logf(z);

    if (lane == 0) {
        const float num = nsum + start_tr[tg[0]] + end_tr[tg[len - 1]];
        out[b] = num - logZ;
    }
}

// ---------------------------------------------------------------------------
extern "C" void kernel_launch(void* const* d_in, const int* in_sizes, int n_in,
                              void* d_out, int out_size, void* d_ws, size_t ws_size,
                              hipStream_t stream) {
    const float* H        = (const float*)d_in[0];
    const float* W        = (const float*)d_in[1];
    const float* bias     = (const float*)d_in[2];
    const float* start_tr = (const float*)d_in[3];
    const float* end_tr   = (const float*)d_in[4];
    const float* trans    = (const float*)d_in[5];
    const int*   tag      = (const int*)d_in[6];
    const int*   s_len    = (const int*)d_in[7];
    // d_in[8] = w_mask, redundant with s_len

    const size_t NSC = (size_t)B_ * S_ * T_;                 // 3,145,728
    float*          scores = (float*)d_ws;                   // 12.6 MB
    float*          logS   = scores + NSC;                   // 8 KB
    unsigned short* Wt     = (unsigned short*)(logS + B_ * NCH);  // 96 KB
    unsigned short* Ptg    = Wt + (size_t)T_ * U_;           // 9.4 MB

    hipLaunchKernelGGL(prep_w, dim3(T_), dim3(256), 0, stream, W, Wt);
    hipLaunchKernelGGL(gemm_scores_mfma, dim3((B_ * S_) / 128), dim3(256), 0,
                       stream, H, Wt, bias, s_len, scores);
    hipLaunchKernelGGL(build_ops, dim3(B_ * NCH / 4), dim3(256), 0, stream,
                       scores, trans, s_len, Ptg, logS);
    hipLaunchKernelGGL(crf_forward, dim3(B_), dim3(64), 0, stream,
                       scores, Ptg, logS, start_tr, end_tr, trans, tag, s_len,
                       (float*)d_out);
}

// Round 5
// 410.553 us; speedup vs baseline: 1.0239x; 1.0239x over previous
//
#include <hip/hip_runtime.h>
#include <math.h>

#define B_  128
#define S_  512
#define U_  1024
#define T_  48
#define CHK 32      // steps per chunk operator
#define NCH 16      // max chunks per batch = ceil((S-1)/CHK)
#define PLD 72      // P row stride in bf16 elems (144 B, 16B-aligned rows)

typedef short  bf16x8 __attribute__((ext_vector_type(8)));
typedef float  f32x4  __attribute__((ext_vector_type(4)));

__device__ __forceinline__ float rfl(float x) {
    return __int_as_float(__builtin_amdgcn_readfirstlane(__float_as_int(x)));
}
// round-to-nearest fp32 -> bf16 bits, packed pairwise
__device__ __forceinline__ unsigned pack_bf16(float lo, float hi) {
    const unsigned a = __float_as_uint(lo) + 0x8000u;
    const unsigned b = __float_as_uint(hi) + 0x8000u;
    return __builtin_amdgcn_perm(b, a, 0x07060302u);
}

// ===========================================================================
// Kernel 0: Wt[n][k] = bf16(W[k][n])  (one-time transpose for gemm B staging)
// ===========================================================================
__global__ __launch_bounds__(256) void prep_w(
    const float* __restrict__ W, unsigned short* __restrict__ Wt)
{
    const int n = blockIdx.x;                 // 48 blocks
#pragma unroll
    for (int i = 0; i < 4; ++i) {
        const int k = threadIdx.x + 256 * i;
        const unsigned u = __float_as_uint(W[(size_t)k * T_ + n]) + 0x8000u;
        Wt[(size_t)n * U_ + k] = (unsigned short)(u >> 16);
    }
}

// ===========================================================================
// Kernel 1: scores = H @ W + b (fp32). MFMA bf16 16x16x32. R2-verified
// staging structure (in-loop pack; NO reg double-buffer — R4 showed it
// regresses, suspected spill). Load-row clamp at s_len kept; NEW: epilogue
// store guard row < len (rows >= len are never read downstream).
// ===========================================================================
#define KC     64
#define HS_LD  72
#define WS_LD  72

__global__ __launch_bounds__(256) void gemm_scores_mfma(
    const float* __restrict__ H, const unsigned short* __restrict__ Wt,
    const float* __restrict__ bias, const int* __restrict__ s_len,
    float* __restrict__ scores)
{
    __shared__ unsigned short Hs[128 * HS_LD];
    __shared__ unsigned short Ws[T_ * WS_LD];

    const int blk = blockIdx.x;
    const int b   = blk >> 2;
    const int s0  = (blk & 3) * 128;
    const int len = s_len[b];
    if (s0 >= len) return;
    const int lim = len - 1 - s0;             // >= 0; clamp row for loads

    const int tid  = threadIdx.x;
    const int wave = tid >> 6;
    const int lane = tid & 63;
    const int m16  = lane & 15;
    const int q    = lane >> 4;
    const int grp  = tid >> 4;
    const int l16  = tid & 15;

    const size_t row0 = (size_t)b * S_ + s0;
    const float* Hg = H + row0 * U_;

    f32x4 acc[2][3];
#pragma unroll
    for (int mt = 0; mt < 2; ++mt)
#pragma unroll
        for (int nt = 0; nt < 3; ++nt) acc[mt][nt] = (f32x4){0.f, 0.f, 0.f, 0.f};

    for (int kc = 0; kc < U_ / KC; ++kc) {
        const int k0 = kc * KC;
#pragma unroll
        for (int p = 0; p < 8; ++p) {
            const int row = p * 16 + grp;
            const int rl  = row < lim ? row : lim;   // clamp: avoid HBM waste
            const float4 h = *reinterpret_cast<const float4*>(
                Hg + (size_t)rl * U_ + k0 + l16 * 4);
            const unsigned p01 = pack_bf16(h.x, h.y);
            const unsigned p23 = pack_bf16(h.z, h.w);
            *reinterpret_cast<uint2*>(&Hs[row * HS_LD + l16 * 4]) =
                make_uint2(p01, p23);
        }
#pragma unroll
        for (int i = 0; i < 2; ++i) {
            const int idx = tid + 256 * i;
            if (idx < 384) {
                const int n = idx >> 3, seg = idx & 7;
                const uint4 w = *reinterpret_cast<const uint4*>(
                    Wt + (size_t)n * U_ + k0 + seg * 8);
                *reinterpret_cast<uint4*>(&Ws[n * WS_LD + seg * 8]) = w;
            }
        }
        __syncthreads();

        bf16x8 afr[2][2], bfr[3][2];
#pragma unroll
        for (int mt = 0; mt < 2; ++mt)
#pragma unroll
            for (int ks = 0; ks < 2; ++ks)
                afr[mt][ks] = *reinterpret_cast<const bf16x8*>(
                    &Hs[(wave * 32 + mt * 16 + m16) * HS_LD + ks * 32 + q * 8]);
#pragma unroll
        for (int nt = 0; nt < 3; ++nt)
#pragma unroll
            for (int ks = 0; ks < 2; ++ks)
                bfr[nt][ks] = *reinterpret_cast<const bf16x8*>(
                    &Ws[(nt * 16 + m16) * WS_LD + ks * 32 + q * 8]);
#pragma unroll
        for (int ks = 0; ks < 2; ++ks)
#pragma unroll
            for (int mt = 0; mt < 2; ++mt)
#pragma unroll
                for (int nt = 0; nt < 3; ++nt)
                    acc[mt][nt] = __builtin_amdgcn_mfma_f32_16x16x32_bf16(
                        afr[mt][ks], bfr[nt][ks], acc[mt][nt], 0, 0, 0);
        __syncthreads();
    }

#pragma unroll
    for (int mt = 0; mt < 2; ++mt)
#pragma unroll
        for (int nt = 0; nt < 3; ++nt) {
            const int col = nt * 16 + m16;
            const float bv = bias[col];
#pragma unroll
            for (int i = 0; i < 4; ++i) {
                const int rloc = s0 + wave * 32 + mt * 16 + q * 4 + i;
                if (rloc < len) {
                    const size_t r = (size_t)b * S_ + rloc;
                    scores[r * T_ + col] = acc[mt][nt][i] + bv;
                }
            }
        }
}

// ===========================================================================
// Kernel 2: build chunk operators with MFMA (parallel scan, chunk = 32 steps,
// PARTIAL chunks included: wave-uniform ns = min(CHK, len - s0) steps, so the
// serial kernel has no scalar tail). One wave per (batch, chunk). Per step
// computes P_new^T = D_em * E^T * P^T; per-step normalization by the lead
// entry, log accumulated. Exports Pt[t][j] = P[j][t] + log-scale.
// (R2-verified, unchanged.)
// ===========================================================================
__global__ __launch_bounds__(256) void build_ops(
    const float* __restrict__ scores, const float* __restrict__ trans,
    const int* __restrict__ s_len,
    unsigned short* __restrict__ Ptg, float* __restrict__ logS)
{
    __shared__ float Eld[T_ * T_];                         // exp(trans)[k][m]
    __shared__ __align__(16) unsigned short Pb[4 * 48 * PLD];

    const int tid  = threadIdx.x;
    const int wid  = tid >> 6;
    const int lane = tid & 63;
    const int m16  = lane & 15;
    const int q    = lane >> 4;

    for (int i = tid; i < T_ * T_; i += 256)
        Eld[i] = __expf(trans[i]);
    __syncthreads();                                       // all waves reach

    const int widx = blockIdx.x * 4 + wid;                 // 0..2047
    const int b    = widx / NCH;
    const int c    = widx % NCH;
    const int len  = s_len[b];
    const int s0   = 1 + c * CHK;
    if (s0 >= len) return;                                 // chunk fully past end
    const int ns   = (len - s0 < CHK) ? (len - s0) : CHK;  // wave-uniform

    unsigned short* Ps = &Pb[wid * 48 * PLD];

    // ---- constant A-fragments of E^T: A[m][k] = E[k][m], k>=48 -> 0 ----
    bf16x8 afr[3][2];
#pragma unroll
    for (int mt = 0; mt < 3; ++mt)
#pragma unroll
        for (int kt = 0; kt < 2; ++kt) {
            union { bf16x8 v; unsigned short s[8]; } u;
#pragma unroll
            for (int j = 0; j < 8; ++j) {
                const int k = kt * 32 + q * 8 + j;
                const int m = mt * 16 + m16;
                const float ev = (k < T_) ? Eld[k * T_ + m] : 0.f;
                u.s[j] = (unsigned short)((__float_as_uint(ev) + 0x8000u) >> 16);
            }
            afr[mt][kt] = u.v;
        }

    // ---- init P = Identity (zeros incl. col pad, then diagonal) ----
    {
        uint4* p4 = reinterpret_cast<uint4*>(Ps);
        const uint4 z = make_uint4(0u, 0u, 0u, 0u);
        for (int i = lane; i < 48 * PLD / 8; i += 64) p4[i] = z;
        __builtin_amdgcn_wave_barrier();
        if (lane < T_) Ps[lane * PLD + lane] = 0x3F80;     // bf16(1.0)
        __builtin_amdgcn_wave_barrier();
    }

    const float* sb = scores + ((size_t)b * S_ + s0) * T_;
    float logacc = 0.f;

    // em prefetch: col block mt*16 + q*4 (+i) -> float4 index mt*4+q
    float4 emld[3];
#pragma unroll
    for (int mt = 0; mt < 3; ++mt)
        emld[mt] = reinterpret_cast<const float4*>(sb)[mt * 4 + q];

    for (int i = 0; i < ns; ++i) {
        float4 em[3];
#pragma unroll
        for (int mt = 0; mt < 3; ++mt) {
            em[mt].x = __expf(emld[mt].x); em[mt].y = __expf(emld[mt].y);
            em[mt].z = __expf(emld[mt].z); em[mt].w = __expf(emld[mt].w);
        }
        if (i + 1 < ns) {
            const float* sn = sb + (i + 1) * T_;
#pragma unroll
            for (int mt = 0; mt < 3; ++mt)
                emld[mt] = reinterpret_cast<const float4*>(sn)[mt * 4 + q];
        }

        // B-fragments: B[k][n] = P^T[k][n] = P[n][k] -> b128 from row n
        bf16x8 bfr[2][3];
#pragma unroll
        for (int kt = 0; kt < 2; ++kt)
#pragma unroll
            for (int nt = 0; nt < 3; ++nt)
                bfr[kt][nt] = *reinterpret_cast<const bf16x8*>(
                    &Ps[(nt * 16 + m16) * PLD + kt * 32 + q * 8]);

        f32x4 acc[3][3];
#pragma unroll
        for (int mt = 0; mt < 3; ++mt)
#pragma unroll
            for (int nt = 0; nt < 3; ++nt) acc[mt][nt] = (f32x4){0.f,0.f,0.f,0.f};
#pragma unroll
        for (int kt = 0; kt < 2; ++kt)
#pragma unroll
            for (int mt = 0; mt < 3; ++mt)
#pragma unroll
                for (int nt = 0; nt < 3; ++nt)
                    acc[mt][nt] = __builtin_amdgcn_mfma_f32_16x16x32_bf16(
                        afr[mt][kt], bfr[kt][nt], acc[mt][nt], 0, 0, 0);

        // normalize by D[0][0]*em[0] (lane 0 holds it), scale rows by em
        const float r    = rfl(acc[0][0][0] * em[0].x);
        const float rinv = __builtin_amdgcn_rcpf(r);
        logacc += __logf(r);
        __builtin_amdgcn_wave_barrier();
#pragma unroll
        for (int mt = 0; mt < 3; ++mt) {
            const float sx = em[mt].x * rinv, sy = em[mt].y * rinv;
            const float sz = em[mt].z * rinv, sw = em[mt].w * rinv;
#pragma unroll
            for (int nt = 0; nt < 3; ++nt) {
                const unsigned lo = pack_bf16(acc[mt][nt][0] * sx,
                                              acc[mt][nt][1] * sy);
                const unsigned hi = pack_bf16(acc[mt][nt][2] * sz,
                                              acc[mt][nt][3] * sw);
                // D[m][n] = P_new[n][m]: row n = nt*16+m16, cols mt*16+q*4..+3
                *reinterpret_cast<uint2*>(
                    &Ps[(nt * 16 + m16) * PLD + mt * 16 + q * 4]) =
                    make_uint2(lo, hi);
            }
        }
        __builtin_amdgcn_wave_barrier();
    }

    // ---- export transposed operator: Pt[t][j] = P[j][t]  (48x48 bf16) ----
    if (lane < T_) {
        unsigned outp[24];
#pragma unroll
        for (int j2 = 0; j2 < 24; ++j2) {
            const unsigned a  = Ps[(2 * j2)     * PLD + lane];
            const unsigned b2 = Ps[(2 * j2 + 1) * PLD + lane];
            outp[j2] = a | (b2 << 16);
        }
        unsigned short* dst =
            Ptg + (((size_t)b * NCH + c) * 48 + lane) * 48;
        uint4* d4 = reinterpret_cast<uint4*>(dst);
#pragma unroll
        for (int t4 = 0; t4 < 6; ++t4)
            d4[t4] = make_uint4(outp[4*t4], outp[4*t4+1],
                                outp[4*t4+2], outp[4*t4+3]);
    }
    if (lane == 0) logS[(size_t)b * NCH + c] = logacc;
}

// ===========================================================================
// Kernel 3: CRF forward + numerator. One wave per batch.
// Pure chunk phase: F = ceil((len-1)/CHK) <= 16 serial steps. Operators are
// prefetched depth-2 (3 rotating register buffers, loop unrolled by 3 so all
// buffer indices are compile-time static -> no scratch, no reg moves).
// Lag-1 normalization invariant unchanged.
// ===========================================================================
#define LOADCH(dst, lsdst, idx)                                          \
    {                                                                    \
        const uint4* p_ = reinterpret_cast<const uint4*>(                \
            Pb_ + (size_t)(idx) * 2304 + (size_t)col * 48);              \
        _Pragma("unroll")                                                \
        for (int i_ = 0; i_ < 6; ++i_) dst[i_] = p_[i_];                 \
        lsdst = Lb[idx];                                                 \
    }

#define CRF_BODY(CUR, CL, N2, N2L, CC)                                   \
    {                                                                    \
        if ((CC) + 2 < F) LOADCH(N2, N2L, (CC) + 2);                     \
        float pr[48];                                                    \
        _Pragma("unroll")                                                \
        for (int i_ = 0; i_ < 6; ++i_) {                                 \
            const uint4 u = CUR[i_];                                     \
            pr[8*i_+0] = __uint_as_float(u.x << 16);                     \
            pr[8*i_+1] = __uint_as_float(u.x & 0xFFFF0000u);             \
            pr[8*i_+2] = __uint_as_float(u.y << 16);                     \
            pr[8*i_+3] = __uint_as_float(u.y & 0xFFFF0000u);             \
            pr[8*i_+4] = __uint_as_float(u.z << 16);                     \
            pr[8*i_+5] = __uint_as_float(u.z & 0xFFFF0000u);             \
            pr[8*i_+6] = __uint_as_float(u.w << 16);                     \
            pr[8*i_+7] = __uint_as_float(u.w & 0xFFFF0000u);             \
        }                                                                \
        wb[par & 1][lane] = v;                                           \
        __builtin_amdgcn_wave_barrier();                                 \
        const float4* a4 = reinterpret_cast<const float4*>(wb[par & 1]); \
        float d0=0.f,d1=0.f,d2=0.f,d3=0.f,d4=0.f,d5=0.f,d6=0.f,d7=0.f;   \
        _Pragma("unroll")                                                \
        for (int j4 = 0; j4 < 6; ++j4) {                                 \
            const float4 pa = a4[2 * j4];                                \
            const float4 pb = a4[2 * j4 + 1];                            \
            d0 = fmaf(pa.x, pr[8*j4+0], d0);                             \
            d1 = fmaf(pa.y, pr[8*j4+1], d1);                             \
            d2 = fmaf(pa.z, pr[8*j4+2], d2);                             \
            d3 = fmaf(pa.w, pr[8*j4+3], d3);                             \
            d4 = fmaf(pb.x, pr[8*j4+4], d4);                             \
            d5 = fmaf(pb.y, pr[8*j4+5], d5);                             \
            d6 = fmaf(pb.z, pr[8*j4+6], d6);                             \
            d7 = fmaf(pb.w, pr[8*j4+7], d7);                             \
        }                                                                \
        __builtin_amdgcn_wave_barrier();                                 \
        const float dt = ((d0 + d4) + (d1 + d5)) + ((d2 + d6) + (d3 + d7));\
        v = dt * invr;                                                   \
        C += lr + CL;                                                    \
        const float r_ = rfl(v);                                         \
        invr = __builtin_amdgcn_rcpf(r_);                                \
        lr   = __logf(r_);                                               \
        par ^= 1;                                                        \
    }

__global__ __launch_bounds__(64) void crf_forward(
    const float* __restrict__ scores, const unsigned short* __restrict__ Ptg,
    const float* __restrict__ logS,
    const float* __restrict__ start_tr, const float* __restrict__ end_tr,
    const float* __restrict__ trans, const int* __restrict__ tag,
    const int* __restrict__ s_len, float* __restrict__ out)
{
    __shared__ float Tr[T_ * T_];
    __shared__ __align__(16) float wb[2][64];

    const int b    = blockIdx.x;
    const int lane = threadIdx.x;

    for (int i = lane; i < T_ * T_; i += 64)
        Tr[i] = trans[i];
    __syncthreads();

    const int len = s_len[b];                       // [1, S]
    const float* sc = scores + (size_t)b * S_ * T_;
    const int*   tg = tag + (size_t)b * S_;

    // ---- numerator ----
    float nsum = 0.f;
    for (int s = lane; s < len; s += 64) {
        const int t = tg[s];
        nsum += sc[s * T_ + t];
        if (s >= 1) nsum += Tr[tg[s - 1] * T_ + t];
    }
#pragma unroll
    for (int off = 32; off >= 1; off >>= 1)
        nsum += __shfl_xor(nsum, off);

    const int col = (lane < T_) ? lane : 0;

    // ---- init from step 0 ----
    const float lp0 = (lane < T_) ? (start_tr[lane] + sc[lane]) : -1e30f;
    const float m0  = rfl(lp0);
    float v = __expf(lp0 - m0);
    float C = m0;
    float invr = 1.0f, lr = 0.0f;
    int par = 0;

    // ---- chunk phase (covers ALL steps 1..len-1) ----
    const int F = (len - 1 + CHK - 1) / CHK;
    const unsigned short* Pb_ = Ptg + (size_t)b * NCH * 48 * 48;
    const float* Lb = logS + (size_t)b * NCH;

    uint4 c0[6], c1[6], c2[6];
    float l0_ = 0.f, l1_ = 0.f, l2_ = 0.f;
    if (F > 0) LOADCH(c0, l0_, 0);
    if (F > 1) LOADCH(c1, l1_, 1);

    int cc = 0;
    while (cc + 3 <= F) {
        CRF_BODY(c0, l0_, c2, l2_, cc);
        CRF_BODY(c1, l1_, c0, l0_, cc + 1);
        CRF_BODY(c2, l2_, c1, l1_, cc + 2);
        cc += 3;
    }
    if (cc < F) {
        CRF_BODY(c0, l0_, c2, l2_, cc); ++cc;
        if (cc < F) { CRF_BODY(c1, l1_, c0, l0_, cc); ++cc; }
    }

    // ---- log_Z = C + log(sum_t v_t * exp(end_t)) ----
    // (pending lr is correctly NOT applied: invariant log(alpha)=log(v)+C)
    float z = (lane < T_) ? v * __expf(end_tr[lane]) : 0.f;
#pragma unroll
    for (int off = 32; off >= 1; off >>= 1)
        z += __shfl_xor(z, off);
    const float logZ = C + __logf(z);

    if (lane == 0) {
        const float num = nsum + start_tr[tg[0]] + end_tr[tg[len - 1]];
        out[b] = num - logZ;
    }
}

// ---------------------------------------------------------------------------
extern "C" void kernel_launch(void* const* d_in, const int* in_sizes, int n_in,
                              void* d_out, int out_size, void* d_ws, size_t ws_size,
                              hipStream_t stream) {
    const float* H        = (const float*)d_in[0];
    const float* W        = (const float*)d_in[1];
    const float* bias     = (const float*)d_in[2];
    const float* start_tr = (const float*)d_in[3];
    const float* end_tr   = (const float*)d_in[4];
    const float* trans    = (const float*)d_in[5];
    const int*   tag      = (const int*)d_in[6];
    const int*   s_len    = (const int*)d_in[7];
    // d_in[8] = w_mask, redundant with s_len

    const size_t NSC = (size_t)B_ * S_ * T_;                 // 3,145,728
    float*          scores = (float*)d_ws;                   // 12.6 MB
    float*          logS   = scores + NSC;                   // 8 KB
    unsigned short* Wt     = (unsigned short*)(logS + B_ * NCH);  // 96 KB
    unsigned short* Ptg    = Wt + (size_t)T_ * U_;           // 9.4 MB

    hipLaunchKernelGGL(prep_w, dim3(T_), dim3(256), 0, stream, W, Wt);
    hipLaunchKernelGGL(gemm_scores_mfma, dim3((B_ * S_) / 128), dim3(256), 0,
                       stream, H, Wt, bias, s_len, scores);
    hipLaunchKernelGGL(build_ops, dim3(B_ * NCH / 4), dim3(256), 0, stream,
                       scores, trans, s_len, Ptg, logS);
    hipLaunchKernelGGL(crf_forward, dim3(B_), dim3(64), 0, stream,
                       scores, Ptg, logS, start_tr, end_tr, trans, tag, s_len,
                       (float*)d_out);
}